// Round 4
// baseline (1795.470 us; speedup 1.0000x reference)
//
#include <hip/hip_runtime.h>
#include <cstdint>
#include <cstddef>

#define TN   8192
#define DD   512
#define NPER 4
#define KNN  5

typedef _Float16 f16x8 __attribute__((ext_vector_type(8)));
typedef float    f32x4 __attribute__((ext_vector_type(4)));

// key = sq_row - 2 * acc / 4096^2  ->  fmaf(acc, -2^-23, sq_row)
#define KSCALE (-1.1920928955078125e-07f)

// ---------------------------------------------------------------------------
// Sorted-5 insert, ascending by (val, idx) — matches stable argsort ties.
// ---------------------------------------------------------------------------
__device__ __forceinline__ void ins5(float v, int ix, float tv[KNN], int ti[KNN]) {
  if (v < tv[4] || (v == tv[4] && ix < ti[4])) {
    tv[4] = v; ti[4] = ix;
#pragma unroll
    for (int s = 4; s > 0; --s) {
      bool sw = (tv[s] < tv[s-1]) || (tv[s] == tv[s-1] && ti[s] < ti[s-1]);
      float nhi = sw ? tv[s-1] : tv[s];
      float nlo = sw ? tv[s]   : tv[s-1];
      int   ihi = sw ? ti[s-1] : ti[s];
      int   ilo = sw ? ti[s]   : ti[s-1];
      tv[s] = nhi; tv[s-1] = nlo;
      ti[s] = ihi; ti[s-1] = ilo;
    }
  }
}

__device__ __forceinline__ void gll16(const void* g, void* l) {
  __builtin_amdgcn_global_load_lds(
      (const __attribute__((address_space(1))) void*)g,
      (__attribute__((address_space(3))) void*)l, 16, 0, 0);
}

// ---------------------------------------------------------------------------
// Kernel 0: hi/lo fp16 split of X*4096.  hi = f16(4096x), lo = f16(4096x - hi)
// ---------------------------------------------------------------------------
__global__ void prep_kernel(const float* __restrict__ X,
                            _Float16* __restrict__ H, _Float16* __restrict__ L) {
  const int g = (int)blockIdx.x * 256 + (int)threadIdx.x;
  const float4 x0 = ((const float4*)X)[2*g];
  const float4 x1 = ((const float4*)X)[2*g + 1];
  float xs[8] = {x0.x, x0.y, x0.z, x0.w, x1.x, x1.y, x1.z, x1.w};
  f16x8 h8, l8;
#pragma unroll
  for (int j = 0; j < 8; ++j) {
    float s = xs[j] * 4096.f;
    _Float16 h = (_Float16)s;
    h8[j] = h;
    l8[j] = (_Float16)(s - (float)h);
  }
  ((f16x8*)H)[g] = h8;
  ((f16x8*)L)[g] = l8;
}

// ---------------------------------------------------------------------------
// Kernel 1: rowsq[r] = sum_d X[r][d]^2   (one wave per row) — exact fp32 X
// ---------------------------------------------------------------------------
__global__ void sq_kernel(const float* __restrict__ X, float* __restrict__ rowsq) {
  const int row  = (int)blockIdx.x * 4 + ((int)threadIdx.x >> 6);
  const int lane = (int)threadIdx.x & 63;
  const float4* xr = (const float4*)(X + (size_t)row * DD);
  float4 a = xr[lane];
  float4 b = xr[lane + 64];
  float s = a.x*a.x + a.y*a.y + a.z*a.z + a.w*a.w
          + b.x*b.x + b.y*b.y + b.z*b.z + b.w*b.w;
#pragma unroll
  for (int off = 32; off >= 1; off >>= 1) s += __shfl_down(s, off, 64);
  if (lane == 0) rowsq[row] = s;
}

// ---------------------------------------------------------------------------
// Kernel 2: fp16 split-MFMA GEMM (K = 3*512: HH + HL + LH), fused column-mode
// top-5. Block 256 thr = 4 waves; block tile 128 rows x 256 cols; wave tile
// 128x64 (8x4 frags of 16x16x32 -> 44 FLOP per LDS byte).
// LDS: 2 bufs x (A 8KB + B 16KB) = 48 KB, staged linear via global_load_lds.
// T2 swizzle (rule #21): LDS row r = 4 slots of 16B; slot q holds global
// k-slot (q ^ ((r>>1)&3)) — pre-swizzled at the global SOURCE; read addr
// row*64 + (lgrp ^ ((lidx>>1)&3))*16 -> uniform slot-position histogram.
// C layout (m89): col = lane&15, row = 4*(lane>>4) + reg.
// Partials: one top5 per (col, 128-row block) -> [8192][64][10B].
// ---------------------------------------------------------------------------
__global__ void gemm_mfma(const _Float16* __restrict__ H, const _Float16* __restrict__ L,
                          const float* __restrict__ rowsq, float* __restrict__ partials) {
  __shared__ __align__(16) char smem[49152];
  const int tid  = (int)threadIdx.x;
  const int lane = tid & 63;
  const int w    = tid >> 6;                  // wave 0..3 -> col quarter
  // XCD-aware swizzle (T1): nwg=2048 % 8 == 0 -> simple form is bijective
  const int bid  = ((int)blockIdx.x & 7) * 256 + ((int)blockIdx.x >> 3);
  const int rb   = bid & 63;                  // 64 row-blocks of 128
  const int cb   = bid >> 6;                  // 32 col-blocks of 256
  const int row0 = rb * 128;
  const int jb   = cb * 256;
  const int lgrp = lane >> 4;                 // k-group / C row-group
  const int lidx = lane & 15;                 // A-row / B-col within frag
  const int srw  = lane >> 2;                 // staging row 0..15
  const int swk  = ((lane & 3) ^ ((srw >> 1) & 3)) * 8;   // swizzled src k-elems
  const int swr  = (lgrp ^ ((lidx >> 1) & 3)) * 16;       // swizzled read bytes

#define STAGE(buf, ksv) do {                                                    \
    const int seg_ = (ksv) >> 4;                                                \
    const int kko_ = ((ksv) & 15) * 32;                                         \
    const _Float16* sA_ = (seg_ == 2) ? L : H;                                  \
    const _Float16* sB_ = (seg_ == 1) ? L : H;                                  \
    char* ab_ = smem + (buf)*24576 + 2048*w;                                    \
    char* bb_ = smem + (buf)*24576 + 8192 + 4096*w;                             \
    gll16(sA_ + (size_t)(row0 + 32*w      + srw)*DD + kko_ + swk, ab_);         \
    gll16(sA_ + (size_t)(row0 + 32*w + 16 + srw)*DD + kko_ + swk, ab_ + 1024);  \
    gll16(sB_ + (size_t)(jb   + 64*w      + srw)*DD + kko_ + swk, bb_);         \
    gll16(sB_ + (size_t)(jb   + 64*w + 16 + srw)*DD + kko_ + swk, bb_ + 1024);  \
    gll16(sB_ + (size_t)(jb   + 64*w + 32 + srw)*DD + kko_ + swk, bb_ + 2048);  \
    gll16(sB_ + (size_t)(jb   + 64*w + 48 + srw)*DD + kko_ + swk, bb_ + 3072);  \
  } while (0)

  f32x4 acc[8][4] = {};

  STAGE(0, 0);
  __syncthreads();

  for (int ks = 0; ks < 48; ++ks) {           // K = 1536 in chunks of 32
    const int cur = ks & 1;
    if (ks < 47) STAGE(cur ^ 1, ks + 1);      // async prefetch into other buffer

    const char* Ab = smem + cur*24576;
    const char* Bb = Ab + 8192;
    f16x8 af[8], bf[4];
#pragma unroll
    for (int t = 0; t < 8; ++t)
      af[t] = *(const f16x8*)(Ab + t*1024 + lidx*64 + swr);
#pragma unroll
    for (int u = 0; u < 4; ++u)
      bf[u] = *(const f16x8*)(Bb + w*4096 + u*1024 + lidx*64 + swr);

#pragma unroll
    for (int t = 0; t < 8; ++t)
#pragma unroll
      for (int u = 0; u < 4; ++u)
        acc[t][u] = __builtin_amdgcn_mfma_f32_16x16x32_f16(af[t], bf[u], acc[t][u], 0, 0, 0);

    __syncthreads();                          // cur consumed + nxt staged
  }

  // ---- fused selection epilogue (column-mode; each wave reduces 128 rows) ----
  float4 sqr[8];
#pragma unroll
  for (int t = 0; t < 8; ++t)
    sqr[t] = *(const float4*)(rowsq + row0 + t*16 + lgrp*4);

#pragma unroll
  for (int cf = 0; cf < 4; ++cf) {
    const int jc = jb + w*64 + cf*16 + lidx;  // this lane's center column
    float tv[KNN]; int ti[KNN];
#pragma unroll
    for (int s = 0; s < KNN; ++s) { tv[s] = 3.4e38f; ti[s] = 0x3fffffff; }
#pragma unroll
    for (int t = 0; t < 8; ++t) {
      const int rbase = row0 + t*16 + lgrp*4;
      float key;
      key = fmaf(acc[t][cf][0], KSCALE, sqr[t].x); if (rbase+0 != jc) ins5(key, rbase+0, tv, ti);
      key = fmaf(acc[t][cf][1], KSCALE, sqr[t].y); if (rbase+1 != jc) ins5(key, rbase+1, tv, ti);
      key = fmaf(acc[t][cf][2], KSCALE, sqr[t].z); if (rbase+2 != jc) ins5(key, rbase+2, tv, ti);
      key = fmaf(acc[t][cf][3], KSCALE, sqr[t].w); if (rbase+3 != jc) ins5(key, rbase+3, tv, ti);
    }
    // merge the 4 lanes (same col, different row-groups): d = 16, 32
#pragma unroll
    for (int d = 16; d <= 32; d <<= 1) {
      float ov[KNN]; int oi[KNN];
#pragma unroll
      for (int s = 0; s < KNN; ++s) {
        ov[s] = __shfl_xor(tv[s], d, 64);
        oi[s] = __shfl_xor(ti[s], d, 64);
      }
#pragma unroll
      for (int s = 0; s < KNN; ++s) ins5(ov[s], oi[s], tv, ti);
    }
    if (lane < 16) {                          // one writer per column
      float* pw = partials + ((size_t)jc * 64 + rb) * 10;
#pragma unroll
      for (int s = 0; s < KNN; ++s) { pw[2*s] = tv[s]; ((int*)pw)[2*s+1] = ti[s]; }
    }
  }
#undef STAGE
}

// ---------------------------------------------------------------------------
// Kernel 3: fold 64 partial top-5 lists per column -> nn[T][5] (sorted).
// One wave per column, one partial per lane.
// ---------------------------------------------------------------------------
__global__ void merge_nn(const float* __restrict__ parts, int* __restrict__ nn) {
  const int j    = (int)blockIdx.x * 4 + ((int)threadIdx.x >> 6);
  const int lane = (int)threadIdx.x & 63;
  float tv[KNN]; int ti[KNN];
#pragma unroll
  for (int s = 0; s < KNN; ++s) { tv[s] = 3.4e38f; ti[s] = 0x3fffffff; }
  const float* p0 = parts + ((size_t)j * 64 + lane) * 10;
#pragma unroll
  for (int s = 0; s < KNN; ++s) ins5(p0[2*s], ((const int*)p0)[2*s+1], tv, ti);
#pragma unroll
  for (int d = 1; d < 64; d <<= 1) {
    float ov[KNN]; int oi[KNN];
#pragma unroll
    for (int s = 0; s < KNN; ++s) {
      ov[s] = __shfl_xor(tv[s], d, 64);
      oi[s] = __shfl_xor(ti[s], d, 64);
    }
#pragma unroll
    for (int s = 0; s < KNN; ++s) ins5(ov[s], oi[s], tv, ti);
  }
  if (lane == 0) {
#pragma unroll
    for (int s = 0; s < KNN; ++s) nn[j*KNN + s] = ti[s];
  }
}

// ---------------------------------------------------------------------------
// Kernel 4: synthesis  out[i*4+p] = x_i + g * (x_nn - x_i)
// ---------------------------------------------------------------------------
__global__ void synth_kernel(const float* __restrict__ X, const int* __restrict__ nn,
                             const float* __restrict__ gaps, const int* __restrict__ choice,
                             float* __restrict__ out) {
  const float4* X4 = (const float4*)X;
  float4* O4 = (float4*)out;
  const int base = (int)blockIdx.x * 256 + (int)threadIdx.x;
#pragma unroll
  for (int it = 0; it < 8; ++it) {
    const int f    = base + it * (2048 * 256);
    const int orow = f >> 7;
    const int d4   = f & 127;
    const int i    = orow >> 2;
    const int ch   = choice[orow];
    const int nr   = nn[i * KNN + ch];
    const float g  = gaps[orow];
    const float4 xi = X4[(size_t)i  * 128 + d4];
    const float4 xn = X4[(size_t)nr * 128 + d4];
    float4 r;
    r.x = fmaf(g, xn.x - xi.x, xi.x);
    r.y = fmaf(g, xn.y - xi.y, xi.y);
    r.z = fmaf(g, xn.z - xi.z, xi.z);
    r.w = fmaf(g, xn.w - xi.w, xi.w);
    O4[(size_t)orow * 128 + d4] = r;
  }
}

// ---------------------------------------------------------------------------
// d_out (64 MB) doubles as scratch: H[8MB] | L[8MB] | partials[20MB] — synth
// fully rewrites d_out last. d_ws holds rowsq + nn (~200 KB).
// ---------------------------------------------------------------------------
extern "C" void kernel_launch(void* const* d_in, const int* in_sizes, int n_in,
                              void* d_out, int out_size, void* d_ws, size_t ws_size,
                              hipStream_t stream) {
  const float* X      = (const float*)d_in[0];
  const float* gaps   = (const float*)d_in[1];
  const int*   choice = (const int*)  d_in[2];
  float* out = (float*)d_out;

  _Float16* Hbuf  = (_Float16*)d_out;                       // [0, 8M)
  _Float16* Lbuf  = (_Float16*)((char*)d_out + 8388608);    // [8M, 16M)
  float*    parts = (float*)((char*)d_out + 16777216);      // [16M, 36M)

  float* rowsq = (float*)d_ws;                              // 32 KB
  int*   nn    = (int*)((char*)d_ws + TN * 4);              // 160 KB

  prep_kernel <<<2048, 256, 0, stream>>>(X, Hbuf, Lbuf);
  sq_kernel   <<<2048, 256, 0, stream>>>(X, rowsq);
  gemm_mfma   <<<2048, 256, 0, stream>>>(Hbuf, Lbuf, rowsq, parts);
  merge_nn    <<<2048, 256, 0, stream>>>(parts, nn);
  synth_kernel<<<2048, 256, 0, stream>>>(X, nn, gaps, choice, out);
}

// Round 5
// 854.254 us; speedup vs baseline: 2.1018x; 2.1018x over previous
//
#include <hip/hip_runtime.h>
#include <cstdint>
#include <cstddef>

#define TN   8192
#define DD   512
#define NPER 4
#define KNN  5

typedef _Float16 f16x8 __attribute__((ext_vector_type(8)));
typedef _Float16 f16x4 __attribute__((ext_vector_type(4)));
typedef float    f32x4 __attribute__((ext_vector_type(4)));

// key = sq_row - 2 * acc / 4096^2  ->  fmaf(acc, -2^-23, sq_row)
#define KSCALE (-1.1920928955078125e-07f)

// ---------------------------------------------------------------------------
// Sorted-5 insert, ascending by (val, idx) — matches stable argsort ties.
// ---------------------------------------------------------------------------
__device__ __forceinline__ void ins5(float v, int ix, float tv[KNN], int ti[KNN]) {
  if (v < tv[4] || (v == tv[4] && ix < ti[4])) {
    tv[4] = v; ti[4] = ix;
#pragma unroll
    for (int s = 4; s > 0; --s) {
      bool sw = (tv[s] < tv[s-1]) || (tv[s] == tv[s-1] && ti[s] < ti[s-1]);
      float nhi = sw ? tv[s-1] : tv[s];
      float nlo = sw ? tv[s]   : tv[s-1];
      int   ihi = sw ? ti[s-1] : ti[s];
      int   ilo = sw ? ti[s]   : ti[s-1];
      tv[s] = nhi; tv[s-1] = nlo;
      ti[s] = ihi; ti[s-1] = ilo;
    }
  }
}

__device__ __forceinline__ void gll16(const void* g, void* l) {
  __builtin_amdgcn_global_load_lds(
      (const __attribute__((address_space(1))) void*)g,
      (__attribute__((address_space(3))) void*)l, 16, 0, 0);
}

// ---------------------------------------------------------------------------
// Kernel 0: fused hi/lo fp16 split of X*4096 AND rowsq. One wave per row.
// ---------------------------------------------------------------------------
__global__ void prep_sq(const float* __restrict__ X,
                        _Float16* __restrict__ H, _Float16* __restrict__ L,
                        float* __restrict__ rowsq) {
  const int row  = (int)blockIdx.x * 4 + ((int)threadIdx.x >> 6);
  const int lane = (int)threadIdx.x & 63;
  const float4* xr = (const float4*)(X + (size_t)row * DD);
  const float4 a = xr[lane];
  const float4 b = xr[lane + 64];
  float xa[4] = {a.x, a.y, a.z, a.w};
  float xb[4] = {b.x, b.y, b.z, b.w};
  f16x4 ha, la, hb, lb;
#pragma unroll
  for (int j = 0; j < 4; ++j) {
    float s = xa[j] * 4096.f;
    _Float16 h = (_Float16)s;
    ha[j] = h; la[j] = (_Float16)(s - (float)h);
    s = xb[j] * 4096.f;
    h = (_Float16)s;
    hb[j] = h; lb[j] = (_Float16)(s - (float)h);
  }
  f16x4* Hr = (f16x4*)(H + (size_t)row * DD);
  f16x4* Lr = (f16x4*)(L + (size_t)row * DD);
  Hr[lane] = ha; Hr[lane + 64] = hb;
  Lr[lane] = la; Lr[lane + 64] = lb;

  float s = a.x*a.x + a.y*a.y + a.z*a.z + a.w*a.w
          + b.x*b.x + b.y*b.y + b.z*b.z + b.w*b.w;
#pragma unroll
  for (int off = 32; off >= 1; off >>= 1) s += __shfl_down(s, off, 64);
  if (lane == 0) rowsq[row] = s;
}

// ---------------------------------------------------------------------------
// Kernel 2: fp16 split-MFMA GEMM (K = 3*512: HH + HL + LH), fused column-mode
// top-5. m97 geometry: block 128x128, 4 waves, wave tile 64x64 (acc 4x4 frags
// = 64 AGPR; af[4]+bf[4] = 32 VGPR — fits the allocator, R4's 128x64 spilled).
// LDS: 2 bufs x (A 8KB + B 8KB) = 32 KB, linear dest via global_load_lds.
// T2 swizzle (rule #21, verified 0-conflict in R4): LDS row r holds global
// k-slot (q ^ ((r>>1)&3)) at 16B-slot q — pre-swizzled at the global SOURCE;
// read addr row*64 + (lgrp ^ ((lidx>>1)&3))*16.
// C layout (m89): col = lane&15, row = 4*(lane>>4) + reg.
// Partials: one top5 per (col, 128-row block, wr) -> [8192][128][10B].
// ---------------------------------------------------------------------------
__launch_bounds__(256, 2)   // relax arch-VGPR cap to 256 unified (demand ~134)
__global__ void gemm_mfma(const _Float16* __restrict__ H, const _Float16* __restrict__ L,
                          const float* __restrict__ rowsq, float* __restrict__ partials) {
  __shared__ __align__(16) char smem[32768];
  const int tid  = (int)threadIdx.x;
  const int lane = tid & 63;
  const int w    = tid >> 6;                  // wave 0..3
  const int wr   = w >> 1, wc = w & 1;        // 2x2 wave grid
  // XCD-aware swizzle (T1): nwg=4096 % 8 == 0 -> bijective
  const int bid  = ((int)blockIdx.x & 7) * 512 + ((int)blockIdx.x >> 3);
  const int rb   = bid & 63;                  // 64 row-blocks of 128
  const int cb   = bid >> 6;                  // 64 col-blocks of 128
  const int row0 = rb * 128;
  const int jb   = cb * 128;
  const int lgrp = lane >> 4;                 // k-group / C row-group
  const int lidx = lane & 15;                 // A-row / B-col within frag
  const int srw  = lane >> 2;                 // staging row 0..15
  const int swk  = ((lane & 3) ^ ((srw >> 1) & 3)) * 8;   // swizzled src k (f16)
  const int swr  = (lgrp ^ ((lidx >> 1) & 3)) * 16;       // swizzled read bytes

#define STAGE(buf, ksv) do {                                                    \
    const int seg_ = (ksv) >> 4;                                                \
    const int kko_ = ((ksv) & 15) * 32;                                         \
    const _Float16* sA_ = (seg_ == 2) ? L : H;                                  \
    const _Float16* sB_ = (seg_ == 1) ? L : H;                                  \
    char* ab_ = smem + (buf)*16384 + 2048*w;                                    \
    char* bb_ = smem + (buf)*16384 + 8192 + 2048*w;                             \
    gll16(sA_ + (size_t)(row0 + 32*w      + srw)*DD + kko_ + swk, ab_);         \
    gll16(sA_ + (size_t)(row0 + 32*w + 16 + srw)*DD + kko_ + swk, ab_ + 1024);  \
    gll16(sB_ + (size_t)(jb   + 32*w      + srw)*DD + kko_ + swk, bb_);         \
    gll16(sB_ + (size_t)(jb   + 32*w + 16 + srw)*DD + kko_ + swk, bb_ + 1024);  \
  } while (0)

  f32x4 acc[4][4] = {};

  STAGE(0, 0);
  __syncthreads();

  for (int ks = 0; ks < 48; ++ks) {           // K = 1536 in chunks of 32
    const int cur = ks & 1;
    if (ks < 47) STAGE(cur ^ 1, ks + 1);      // async prefetch into other buffer

    const char* Ab = smem + cur*16384;
    const char* Bb = Ab + 8192;
    f16x8 af[4], bf[4];
#pragma unroll
    for (int t = 0; t < 4; ++t) {
      af[t] = *(const f16x8*)(Ab + (wr*4+t)*1024 + lidx*64 + swr);
      bf[t] = *(const f16x8*)(Bb + (wc*4+t)*1024 + lidx*64 + swr);
    }
#pragma unroll
    for (int rt = 0; rt < 4; ++rt)
#pragma unroll
      for (int cf = 0; cf < 4; ++cf)
        acc[rt][cf] = __builtin_amdgcn_mfma_f32_16x16x32_f16(af[rt], bf[cf], acc[rt][cf], 0, 0, 0);

    __syncthreads();                          // cur consumed + nxt staged
  }

  // ---- fused selection epilogue (column-mode; wave reduces its 64 rows) ----
  float4 sqr[4];
#pragma unroll
  for (int t = 0; t < 4; ++t)
    sqr[t] = *(const float4*)(rowsq + row0 + wr*64 + t*16 + lgrp*4);

#pragma unroll
  for (int cf = 0; cf < 4; ++cf) {
    const int jc = jb + wc*64 + cf*16 + lidx; // this lane's center column
    float tv[KNN]; int ti[KNN];
#pragma unroll
    for (int s = 0; s < KNN; ++s) { tv[s] = 3.4e38f; ti[s] = 0x3fffffff; }
#pragma unroll
    for (int t = 0; t < 4; ++t) {
      const int rbase = row0 + wr*64 + t*16 + lgrp*4;
      float key;
      key = fmaf(acc[t][cf][0], KSCALE, sqr[t].x); if (rbase+0 != jc) ins5(key, rbase+0, tv, ti);
      key = fmaf(acc[t][cf][1], KSCALE, sqr[t].y); if (rbase+1 != jc) ins5(key, rbase+1, tv, ti);
      key = fmaf(acc[t][cf][2], KSCALE, sqr[t].z); if (rbase+2 != jc) ins5(key, rbase+2, tv, ti);
      key = fmaf(acc[t][cf][3], KSCALE, sqr[t].w); if (rbase+3 != jc) ins5(key, rbase+3, tv, ti);
    }
    // merge the 4 lanes (same col, different row-groups): d = 16, 32
#pragma unroll
    for (int d = 16; d <= 32; d <<= 1) {
      float ov[KNN]; int oi[KNN];
#pragma unroll
      for (int s = 0; s < KNN; ++s) {
        ov[s] = __shfl_xor(tv[s], d, 64);
        oi[s] = __shfl_xor(ti[s], d, 64);
      }
#pragma unroll
      for (int s = 0; s < KNN; ++s) ins5(ov[s], oi[s], tv, ti);
    }
    if (lane < 16) {                          // one writer per column
      float* pw = partials + ((size_t)jc * 128 + rb*2 + wr) * 10;
#pragma unroll
      for (int s = 0; s < KNN; ++s) { pw[2*s] = tv[s]; ((int*)pw)[2*s+1] = ti[s]; }
    }
  }
#undef STAGE
}

// ---------------------------------------------------------------------------
// Kernel 3: fold 128 partial top-5 lists per column -> nn[T][5] (sorted).
// One wave per column, two partials per lane.
// ---------------------------------------------------------------------------
__global__ void merge_nn(const float* __restrict__ parts, int* __restrict__ nn) {
  const int j    = (int)blockIdx.x * 4 + ((int)threadIdx.x >> 6);
  const int lane = (int)threadIdx.x & 63;
  float tv[KNN]; int ti[KNN];
#pragma unroll
  for (int s = 0; s < KNN; ++s) { tv[s] = 3.4e38f; ti[s] = 0x3fffffff; }
  const float* p0 = parts + ((size_t)j * 128 + lane) * 10;
  const float* p1 = parts + ((size_t)j * 128 + lane + 64) * 10;
#pragma unroll
  for (int s = 0; s < KNN; ++s) ins5(p0[2*s], ((const int*)p0)[2*s+1], tv, ti);
#pragma unroll
  for (int s = 0; s < KNN; ++s) ins5(p1[2*s], ((const int*)p1)[2*s+1], tv, ti);
#pragma unroll
  for (int d = 1; d < 64; d <<= 1) {
    float ov[KNN]; int oi[KNN];
#pragma unroll
    for (int s = 0; s < KNN; ++s) {
      ov[s] = __shfl_xor(tv[s], d, 64);
      oi[s] = __shfl_xor(ti[s], d, 64);
    }
#pragma unroll
    for (int s = 0; s < KNN; ++s) ins5(ov[s], oi[s], tv, ti);
  }
  if (lane == 0) {
#pragma unroll
    for (int s = 0; s < KNN; ++s) nn[j*KNN + s] = ti[s];
  }
}

// ---------------------------------------------------------------------------
// Kernel 4: synthesis  out[i*4+p] = x_i + g * (x_nn - x_i)
// ---------------------------------------------------------------------------
__global__ void synth_kernel(const float* __restrict__ X, const int* __restrict__ nn,
                             const float* __restrict__ gaps, const int* __restrict__ choice,
                             float* __restrict__ out) {
  const float4* X4 = (const float4*)X;
  float4* O4 = (float4*)out;
  const int base = (int)blockIdx.x * 256 + (int)threadIdx.x;
#pragma unroll
  for (int it = 0; it < 8; ++it) {
    const int f    = base + it * (2048 * 256);
    const int orow = f >> 7;
    const int d4   = f & 127;
    const int i    = orow >> 2;
    const int ch   = choice[orow];
    const int nr   = nn[i * KNN + ch];
    const float g  = gaps[orow];
    const float4 xi = X4[(size_t)i  * 128 + d4];
    const float4 xn = X4[(size_t)nr * 128 + d4];
    float4 r;
    r.x = fmaf(g, xn.x - xi.x, xi.x);
    r.y = fmaf(g, xn.y - xi.y, xi.y);
    r.z = fmaf(g, xn.z - xi.z, xi.z);
    r.w = fmaf(g, xn.w - xi.w, xi.w);
    O4[(size_t)orow * 128 + d4] = r;
  }
}

// ---------------------------------------------------------------------------
// d_out (64 MB) doubles as scratch: H[8MB] | L[8MB] | partials[42MB] — synth
// fully rewrites d_out last. d_ws holds rowsq + nn (~200 KB).
// ---------------------------------------------------------------------------
extern "C" void kernel_launch(void* const* d_in, const int* in_sizes, int n_in,
                              void* d_out, int out_size, void* d_ws, size_t ws_size,
                              hipStream_t stream) {
  const float* X      = (const float*)d_in[0];
  const float* gaps   = (const float*)d_in[1];
  const int*   choice = (const int*)  d_in[2];
  float* out = (float*)d_out;

  _Float16* Hbuf  = (_Float16*)d_out;                       // [0, 8M)
  _Float16* Lbuf  = (_Float16*)((char*)d_out + 8388608);    // [8M, 16M)
  float*    parts = (float*)((char*)d_out + 16777216);      // [16M, 58M)

  float* rowsq = (float*)d_ws;                              // 32 KB
  int*   nn    = (int*)((char*)d_ws + TN * 4);              // 160 KB

  prep_sq     <<<2048, 256, 0, stream>>>(X, Hbuf, Lbuf, rowsq);
  gemm_mfma   <<<4096, 256, 0, stream>>>(Hbuf, Lbuf, rowsq, parts);
  merge_nn    <<<2048, 256, 0, stream>>>(parts, nn);
  synth_kernel<<<2048, 256, 0, stream>>>(X, nn, gaps, choice, out);
}